// Round 12
// baseline (436.098 us; speedup 1.0000x reference)
//
#include <hip/hip_runtime.h>
#include <math.h>

#define EPS 1e-7f
#define MAX_NORM (1.0f - 1e-5f)
#define SCAN_CHUNK 1024   // elements per scan block (256 thr x 4)

__device__ __forceinline__ float waveReduceSum(float v) {
    #pragma unroll
    for (int off = 32; off > 0; off >>= 1) v += __shfl_xor(v, off, 64);
    return v;
}

// ---------------------------------------------------------------------------
// Phase 1: hyperbolic transform.
// r9: matvec uses __shfl broadcast of the already-loaded xv register instead
// of re-reading xrow[k] from memory (was 16 KB of uniform L1 traffic per row),
// with 4 independent accumulators for ILP.
// ---------------------------------------------------------------------------
__global__ __launch_bounds__(256) void transform_kernel(
    const float* __restrict__ x, const float* __restrict__ weight,
    const float* __restrict__ bias, float* __restrict__ h, int N)
{
    __shared__ float wlds[64 * 64];
    __shared__ float bh[64];

    const int tid  = threadIdx.x;
    const int lane = tid & 63;
    const int wave = tid >> 6;

    for (int idx = tid; idx < 64 * 64; idx += 256) wlds[idx] = weight[idx];
    __syncthreads();

    for (int r = wave; r < 64; r += 4) {
        float v  = wlds[r * 64 + lane];
        float ss = waveReduceSum(v * v);
        float n  = fmaxf(sqrtf(ss), EPS);
        wlds[r * 64 + lane] = v * (tanhf(n) / n);
    }
    if (wave == 0) {
        float b  = bias[lane];
        float ss = waveReduceSum(b * b);
        float n  = fmaxf(sqrtf(ss), EPS);
        bh[lane] = b * (tanhf(n) / n);
    }
    __syncthreads();

    const float bd = bh[lane];
    const float y2 = waveReduceSum(bd * bd);

    const int gw = blockIdx.x * 4 + wave;
    const int nw = gridDim.x * 4;
    for (int i = gw; i < N; i += nw) {
        const float xv = x[(size_t)i * 64 + lane];
        float ss = waveReduceSum(xv * xv);
        float xn = fmaxf(sqrtf(ss), EPS);
        float xc = fminf(xn, 1.0f - 1e-7f);
        float at = 0.5f * log1pf(2.0f * xc / (1.0f - xc));
        // Mx[lane] = sum_k x[k]*W[k][lane]; x[k] via register broadcast
        float a0 = 0.f, a1 = 0.f, a2 = 0.f, a3 = 0.f;
        #pragma unroll
        for (int k = 0; k < 64; k += 4) {
            a0 = fmaf(__shfl(xv, k + 0, 64), wlds[(k + 0) * 64 + lane], a0);
            a1 = fmaf(__shfl(xv, k + 1, 64), wlds[(k + 1) * 64 + lane], a1);
            a2 = fmaf(__shfl(xv, k + 2, 64), wlds[(k + 2) * 64 + lane], a2);
            a3 = fmaf(__shfl(xv, k + 3, 64), wlds[(k + 3) * 64 + lane], a3);
        }
        float acc = (a0 + a1) + (a2 + a3);
        float mss = waveReduceSum(acc * acc);
        float mxn = fmaxf(sqrtf(mss), EPS);
        float hv  = acc * (tanhf(mxn / xn * at) / mxn);
        float x2 = waveReduceSum(hv * hv);
        float xy = waveReduceSum(hv * bd);
        float num = (1.0f + 2.0f * xy + y2) * hv + (1.0f - x2) * bd;
        float den = 1.0f + 2.0f * xy + x2 * y2;
        h[(size_t)i * 64 + lane] = num / fmaxf(den, EPS);
    }
}

// ---------------------------------------------------------------------------
// Phase 2a: degree histogram (int atomics only)
// ---------------------------------------------------------------------------
__global__ __launch_bounds__(256) void hist_kernel(
    const int* __restrict__ dst, int* __restrict__ cnt, int E)
{
    const int stride = gridDim.x * blockDim.x;
    for (int e = blockIdx.x * blockDim.x + threadIdx.x; e < E; e += stride)
        atomicAdd(&cnt[dst[e]], 1);
}

// ---------------------------------------------------------------------------
// Phase 2b: exclusive scan of cnt -> rowptr (+cursor copy)
// ---------------------------------------------------------------------------
__global__ __launch_bounds__(256) void scan_partial(
    const int* __restrict__ cnt, int* __restrict__ pre,
    int* __restrict__ part, int n)
{
    __shared__ int s[256];
    const int tid  = threadIdx.x;
    const int base = blockIdx.x * SCAN_CHUNK + tid * 4;
    int v0 = (base + 0 < n) ? cnt[base + 0] : 0;
    int v1 = (base + 1 < n) ? cnt[base + 1] : 0;
    int v2 = (base + 2 < n) ? cnt[base + 2] : 0;
    int v3 = (base + 3 < n) ? cnt[base + 3] : 0;
    int tsum = v0 + v1 + v2 + v3;
    s[tid] = tsum;
    __syncthreads();
    for (int off = 1; off < 256; off <<= 1) {
        int t = (tid >= off) ? s[tid - off] : 0;
        __syncthreads();
        s[tid] += t;
        __syncthreads();
    }
    int excl = s[tid] - tsum;
    if (base + 0 < n) pre[base + 0] = excl;
    if (base + 1 < n) pre[base + 1] = excl + v0;
    if (base + 2 < n) pre[base + 2] = excl + v0 + v1;
    if (base + 3 < n) pre[base + 3] = excl + v0 + v1 + v2;
    if (tid == 255) part[blockIdx.x] = s[255];
}

__global__ __launch_bounds__(256) void scan_parts(int* __restrict__ part, int nPart)
{
    __shared__ int s[256];
    const int tid = threadIdx.x;
    int v = (tid < nPart) ? part[tid] : 0;
    s[tid] = v;
    __syncthreads();
    for (int off = 1; off < 256; off <<= 1) {
        int t = (tid >= off) ? s[tid - off] : 0;
        __syncthreads();
        s[tid] += t;
        __syncthreads();
    }
    if (tid < nPart) part[tid] = s[tid] - v;  // exclusive
}

__global__ __launch_bounds__(256) void scan_add(
    int* __restrict__ pre, int* __restrict__ cursor,
    const int* __restrict__ part, int n)
{
    const int stride = gridDim.x * blockDim.x;
    for (int i = blockIdx.x * blockDim.x + threadIdx.x; i < n; i += stride) {
        int v = pre[i] + part[i / SCAN_CHUNK];
        pre[i] = v;        // rowptr
        cursor[i] = v;     // bucket cursor
    }
}

// ---------------------------------------------------------------------------
// Phase 2c: XCD-partitioned bucket scatter (unchanged from r8 — it worked:
// dropped out of top-5).
// ---------------------------------------------------------------------------
__global__ __launch_bounds__(256) void bucket_kernel(
    const int* __restrict__ src, const int* __restrict__ dst,
    int* __restrict__ cursor, int* __restrict__ bucket, int E, int N)
{
    const int group = blockIdx.x & 7;
    const int gblk  = blockIdx.x >> 3;
    const int nblk  = gridDim.x >> 3;
    const int lo = (int)(((long long)N * group) >> 3);
    const int hi = (int)(((long long)N * (group + 1)) >> 3);
    const int stride = nblk * 256;
    for (int e = gblk * 256 + threadIdx.x; e < E; e += stride) {
        const int d = dst[e];
        if (d >= lo && d < hi) {
            int pos = atomicAdd(&cursor[d], 1);
            bucket[pos] = src[e];
        }
    }
}

// ---------------------------------------------------------------------------
// Phase 3: per-node gather-reduce + mean + projection.
// r9: 4 independent accumulators -> 4 gather loads in flight per wave
// (was a serial shfl->load->acc chain, measured latency-bound at 24% HBM).
// ---------------------------------------------------------------------------
__global__ __launch_bounds__(256) void gather_reduce_kernel(
    const int* __restrict__ rowptr, const int* __restrict__ cnt,
    const int* __restrict__ bucket, const float* __restrict__ h,
    float* __restrict__ out, int N)
{
    const int lane = threadIdx.x & 63;
    const int wave = threadIdx.x >> 6;
    const int i = blockIdx.x * 4 + wave;
    if (i >= N) return;

    const int start = rowptr[i];
    const int deg   = cnt[i];
    const int end   = start + deg;

    float a0 = 0.f, a1 = 0.f, a2 = 0.f, a3 = 0.f;
    for (int c = start; c < end; c += 64) {
        const int m  = min(64, end - c);
        const int my = (lane < m) ? bucket[c + lane] : 0;
        int j = 0;
        for (; j + 4 <= m; j += 4) {
            const int s0 = __shfl(my, j + 0, 64);
            const int s1 = __shfl(my, j + 1, 64);
            const int s2 = __shfl(my, j + 2, 64);
            const int s3 = __shfl(my, j + 3, 64);
            a0 += h[(size_t)s0 * 64 + lane];
            a1 += h[(size_t)s1 * 64 + lane];
            a2 += h[(size_t)s2 * 64 + lane];
            a3 += h[(size_t)s3 * 64 + lane];
        }
        for (; j < m; ++j) {
            const int s = __shfl(my, j, 64);
            a0 += h[(size_t)s * 64 + lane];
        }
    }
    float acc = (a0 + a1) + (a2 + a3);

    float v = acc / fmaxf((float)deg, 1.0f);
    float ss = waveReduceSum(v * v);
    float n  = fmaxf(sqrtf(ss), EPS);
    if (n > MAX_NORM) v = v / n * MAX_NORM;
    out[(size_t)i * 64 + lane] = v;
}

extern "C" void kernel_launch(void* const* d_in, const int* in_sizes, int n_in,
                              void* d_out, int out_size, void* d_ws, size_t ws_size,
                              hipStream_t stream)
{
    const float* x      = (const float*)d_in[0];
    const float* weight = (const float*)d_in[1];
    const float* bias   = (const float*)d_in[2];
    const int*   ei     = (const int*)d_in[3];
    const int N = in_sizes[0] / 64;
    const int E = in_sizes[3] / 2;
    const int* src = ei;
    const int* dst = ei + E;

    float* out = (float*)d_out;

    // workspace layout (~33 MB)
    float* h      = (float*)d_ws;               // N*64 floats
    int*   cnt    = (int*)(h + (size_t)N * 64); // N
    int*   rowptr = cnt + N;                    // N
    int*   cursor = rowptr + N;                 // N
    int*   part   = cursor + N;                 // 256
    int*   bucket = part + 256;                 // E

    const int nPart = (N + SCAN_CHUNK - 1) / SCAN_CHUNK;   // 98 for N=100K

    hipMemsetAsync(cnt, 0, (size_t)N * sizeof(int), stream);

    transform_kernel<<<2048, 256, 0, stream>>>(x, weight, bias, h, N);
    hist_kernel<<<2048, 256, 0, stream>>>(dst, cnt, E);
    scan_partial<<<nPart, 256, 0, stream>>>(cnt, rowptr, part, N);
    scan_parts<<<1, 256, 0, stream>>>(part, nPart);
    scan_add<<<256, 256, 0, stream>>>(rowptr, cursor, part, N);
    bucket_kernel<<<2048, 256, 0, stream>>>(src, dst, cursor, bucket, E, N);
    gather_reduce_kernel<<<(N + 3) / 4, 256, 0, stream>>>(rowptr, cnt, bucket, h, out, N);
}

// Round 13
// 339.770 us; speedup vs baseline: 1.2835x; 1.2835x over previous
//
#include <hip/hip_runtime.h>
#include <math.h>

#define EPS 1e-7f
#define MAX_NORM (1.0f - 1e-5f)
#define SCAN_CHUNK 1024   // elements per scan block (256 thr x 4)

__device__ __forceinline__ float waveReduceSum(float v) {
    #pragma unroll
    for (int off = 32; off > 0; off >>= 1) v += __shfl_xor(v, off, 64);
    return v;
}

// ---------------------------------------------------------------------------
// Phase 1: hyperbolic transform.
// r13: ONE THREAD PER ROW. r12's shfl-broadcast regressed (ds_bpermute on the
// LDS pipe + occupancy 43->30%); r8 analysis shows the true cost was four
// 6-step latency-serial wave reductions per row. Thread-per-row removes ALL
// cross-lane ops: 64-dim accumulator in 16 float4 regs (static indices),
// W rows read as uniform-address LDS float4 broadcasts, norms as per-thread
// register reductions.
// ---------------------------------------------------------------------------
__global__ __launch_bounds__(256) void transform_kernel(
    const float* __restrict__ x, const float* __restrict__ weight,
    const float* __restrict__ bias, float* __restrict__ h, int N)
{
    __shared__ float wlds[64 * 64];
    __shared__ float bh[64];

    const int tid  = threadIdx.x;
    const int lane = tid & 63;
    const int wave = tid >> 6;

    for (int idx = tid; idx < 64 * 64; idx += 256) wlds[idx] = weight[idx];
    __syncthreads();

    // expmap0 on each W row + bias (once per block; wave reductions fine here)
    for (int r = wave; r < 64; r += 4) {
        float v  = wlds[r * 64 + lane];
        float ss = waveReduceSum(v * v);
        float n  = fmaxf(sqrtf(ss), EPS);
        wlds[r * 64 + lane] = v * (tanhf(n) / n);
    }
    if (wave == 0) {
        float b  = bias[lane];
        float ss = waveReduceSum(b * b);
        float n  = fmaxf(sqrtf(ss), EPS);
        bh[lane] = b * (tanhf(n) / n);
    }
    __syncthreads();

    const float4* __restrict__ w4  = reinterpret_cast<const float4*>(wlds);
    const float4* __restrict__ bh4 = reinterpret_cast<const float4*>(bh);

    const int stride = gridDim.x * blockDim.x;
    for (int row = blockIdx.x * blockDim.x + tid; row < N; row += stride) {
        const float4* xr = reinterpret_cast<const float4*>(x + (size_t)row * 64);

        float4 acc[16];
        #pragma unroll
        for (int d = 0; d < 16; ++d) acc[d] = make_float4(0.f, 0.f, 0.f, 0.f);
        float ss = 0.f;

        #pragma unroll 2
        for (int k4 = 0; k4 < 16; ++k4) {
            const float4 xq = xr[k4];
            ss = fmaf(xq.x, xq.x, fmaf(xq.y, xq.y, fmaf(xq.z, xq.z, fmaf(xq.w, xq.w, ss))));
            const float xs0 = xq.x, xs1 = xq.y, xs2 = xq.z, xs3 = xq.w;
            const float4* wr0 = w4 + (k4 * 4 + 0) * 16;
            const float4* wr1 = w4 + (k4 * 4 + 1) * 16;
            const float4* wr2 = w4 + (k4 * 4 + 2) * 16;
            const float4* wr3 = w4 + (k4 * 4 + 3) * 16;
            #pragma unroll
            for (int d = 0; d < 16; ++d) {
                float4 w0 = wr0[d], w1 = wr1[d], w2 = wr2[d], w3 = wr3[d];
                float4 a = acc[d];
                a.x = fmaf(xs0, w0.x, a.x); a.y = fmaf(xs0, w0.y, a.y);
                a.z = fmaf(xs0, w0.z, a.z); a.w = fmaf(xs0, w0.w, a.w);
                a.x = fmaf(xs1, w1.x, a.x); a.y = fmaf(xs1, w1.y, a.y);
                a.z = fmaf(xs1, w1.z, a.z); a.w = fmaf(xs1, w1.w, a.w);
                a.x = fmaf(xs2, w2.x, a.x); a.y = fmaf(xs2, w2.y, a.y);
                a.z = fmaf(xs2, w2.z, a.z); a.w = fmaf(xs2, w2.w, a.w);
                a.x = fmaf(xs3, w3.x, a.x); a.y = fmaf(xs3, w3.y, a.y);
                a.z = fmaf(xs3, w3.z, a.z); a.w = fmaf(xs3, w3.w, a.w);
                acc[d] = a;
            }
        }

        // norms + tanh scaling (all per-thread scalar)
        float mss = 0.f;
        #pragma unroll
        for (int d = 0; d < 16; ++d) {
            float4 a = acc[d];
            mss = fmaf(a.x, a.x, fmaf(a.y, a.y, fmaf(a.z, a.z, fmaf(a.w, a.w, mss))));
        }
        const float xn  = fmaxf(sqrtf(ss), EPS);
        const float mxn = fmaxf(sqrtf(mss), EPS);
        const float xc  = fminf(xn, 1.0f - 1e-7f);
        const float at  = 0.5f * log1pf(2.0f * xc / (1.0f - xc));
        const float scale = tanhf(mxn / xn * at) / mxn;

        // mobius_add(h, bh): x2 = scale^2*mss; xy, y2 via bh broadcast reads
        float dotab = 0.f, y2 = 0.f;
        #pragma unroll
        for (int d = 0; d < 16; ++d) {
            float4 b = bh4[d];
            float4 a = acc[d];
            dotab = fmaf(a.x, b.x, fmaf(a.y, b.y, fmaf(a.z, b.z, fmaf(a.w, b.w, dotab))));
            y2    = fmaf(b.x, b.x, fmaf(b.y, b.y, fmaf(b.z, b.z, fmaf(b.w, b.w, y2))));
        }
        const float xy = scale * dotab;
        const float x2 = scale * scale * mss;
        const float A  = 1.0f + 2.0f * xy + y2;
        const float B  = 1.0f - x2;
        const float rden = 1.0f / fmaxf(1.0f + 2.0f * xy + x2 * y2, EPS);

        float4* hr = reinterpret_cast<float4*>(h + (size_t)row * 64);
        #pragma unroll
        for (int d = 0; d < 16; ++d) {
            float4 b = bh4[d];
            float4 a = acc[d];
            float4 r;
            r.x = (A * (a.x * scale) + B * b.x) * rden;
            r.y = (A * (a.y * scale) + B * b.y) * rden;
            r.z = (A * (a.z * scale) + B * b.z) * rden;
            r.w = (A * (a.w * scale) + B * b.w) * rden;
            hr[d] = r;
        }
    }
}

// ---------------------------------------------------------------------------
// Phase 2a: degree histogram (int atomics only)
// ---------------------------------------------------------------------------
__global__ __launch_bounds__(256) void hist_kernel(
    const int* __restrict__ dst, int* __restrict__ cnt, int E)
{
    const int stride = gridDim.x * blockDim.x;
    for (int e = blockIdx.x * blockDim.x + threadIdx.x; e < E; e += stride)
        atomicAdd(&cnt[dst[e]], 1);
}

// ---------------------------------------------------------------------------
// Phase 2b: exclusive scan of cnt -> rowptr (+cursor copy)
// ---------------------------------------------------------------------------
__global__ __launch_bounds__(256) void scan_partial(
    const int* __restrict__ cnt, int* __restrict__ pre,
    int* __restrict__ part, int n)
{
    __shared__ int s[256];
    const int tid  = threadIdx.x;
    const int base = blockIdx.x * SCAN_CHUNK + tid * 4;
    int v0 = (base + 0 < n) ? cnt[base + 0] : 0;
    int v1 = (base + 1 < n) ? cnt[base + 1] : 0;
    int v2 = (base + 2 < n) ? cnt[base + 2] : 0;
    int v3 = (base + 3 < n) ? cnt[base + 3] : 0;
    int tsum = v0 + v1 + v2 + v3;
    s[tid] = tsum;
    __syncthreads();
    for (int off = 1; off < 256; off <<= 1) {
        int t = (tid >= off) ? s[tid - off] : 0;
        __syncthreads();
        s[tid] += t;
        __syncthreads();
    }
    int excl = s[tid] - tsum;
    if (base + 0 < n) pre[base + 0] = excl;
    if (base + 1 < n) pre[base + 1] = excl + v0;
    if (base + 2 < n) pre[base + 2] = excl + v0 + v1;
    if (base + 3 < n) pre[base + 3] = excl + v0 + v1 + v2;
    if (tid == 255) part[blockIdx.x] = s[255];
}

__global__ __launch_bounds__(256) void scan_parts(int* __restrict__ part, int nPart)
{
    __shared__ int s[256];
    const int tid = threadIdx.x;
    int v = (tid < nPart) ? part[tid] : 0;
    s[tid] = v;
    __syncthreads();
    for (int off = 1; off < 256; off <<= 1) {
        int t = (tid >= off) ? s[tid - off] : 0;
        __syncthreads();
        s[tid] += t;
        __syncthreads();
    }
    if (tid < nPart) part[tid] = s[tid] - v;  // exclusive
}

__global__ __launch_bounds__(256) void scan_add(
    int* __restrict__ pre, int* __restrict__ cursor,
    const int* __restrict__ part, int n)
{
    const int stride = gridDim.x * blockDim.x;
    for (int i = blockIdx.x * blockDim.x + threadIdx.x; i < n; i += stride) {
        int v = pre[i] + part[i / SCAN_CHUNK];
        pre[i] = v;        // rowptr
        cursor[i] = v;     // bucket cursor
    }
}

// ---------------------------------------------------------------------------
// Phase 2c: XCD-partitioned bucket scatter (r8; proven — dropped out of top-5)
// ---------------------------------------------------------------------------
__global__ __launch_bounds__(256) void bucket_kernel(
    const int* __restrict__ src, const int* __restrict__ dst,
    int* __restrict__ cursor, int* __restrict__ bucket, int E, int N)
{
    const int group = blockIdx.x & 7;
    const int gblk  = blockIdx.x >> 3;
    const int nblk  = gridDim.x >> 3;
    const int lo = (int)(((long long)N * group) >> 3);
    const int hi = (int)(((long long)N * (group + 1)) >> 3);
    const int stride = nblk * 256;
    for (int e = gblk * 256 + threadIdx.x; e < E; e += stride) {
        const int d = dst[e];
        if (d >= lo && d < hi) {
            int pos = atomicAdd(&cursor[d], 1);
            bucket[pos] = src[e];
        }
    }
}

// ---------------------------------------------------------------------------
// Phase 3: per-node gather-reduce + mean + projection (r9 4-acc ILP; proven —
// dropped below transform in top-5)
// ---------------------------------------------------------------------------
__global__ __launch_bounds__(256) void gather_reduce_kernel(
    const int* __restrict__ rowptr, const int* __restrict__ cnt,
    const int* __restrict__ bucket, const float* __restrict__ h,
    float* __restrict__ out, int N)
{
    const int lane = threadIdx.x & 63;
    const int wave = threadIdx.x >> 6;
    const int i = blockIdx.x * 4 + wave;
    if (i >= N) return;

    const int start = rowptr[i];
    const int deg   = cnt[i];
    const int end   = start + deg;

    float a0 = 0.f, a1 = 0.f, a2 = 0.f, a3 = 0.f;
    for (int c = start; c < end; c += 64) {
        const int m  = min(64, end - c);
        const int my = (lane < m) ? bucket[c + lane] : 0;
        int j = 0;
        for (; j + 4 <= m; j += 4) {
            const int s0 = __shfl(my, j + 0, 64);
            const int s1 = __shfl(my, j + 1, 64);
            const int s2 = __shfl(my, j + 2, 64);
            const int s3 = __shfl(my, j + 3, 64);
            a0 += h[(size_t)s0 * 64 + lane];
            a1 += h[(size_t)s1 * 64 + lane];
            a2 += h[(size_t)s2 * 64 + lane];
            a3 += h[(size_t)s3 * 64 + lane];
        }
        for (; j < m; ++j) {
            const int s = __shfl(my, j, 64);
            a0 += h[(size_t)s * 64 + lane];
        }
    }
    float acc = (a0 + a1) + (a2 + a3);

    float v = acc / fmaxf((float)deg, 1.0f);
    float ss = waveReduceSum(v * v);
    float n  = fmaxf(sqrtf(ss), EPS);
    if (n > MAX_NORM) v = v / n * MAX_NORM;
    out[(size_t)i * 64 + lane] = v;
}

extern "C" void kernel_launch(void* const* d_in, const int* in_sizes, int n_in,
                              void* d_out, int out_size, void* d_ws, size_t ws_size,
                              hipStream_t stream)
{
    const float* x      = (const float*)d_in[0];
    const float* weight = (const float*)d_in[1];
    const float* bias   = (const float*)d_in[2];
    const int*   ei     = (const int*)d_in[3];
    const int N = in_sizes[0] / 64;
    const int E = in_sizes[3] / 2;
    const int* src = ei;
    const int* dst = ei + E;

    float* out = (float*)d_out;

    // workspace layout (~33 MB)
    float* h      = (float*)d_ws;               // N*64 floats
    int*   cnt    = (int*)(h + (size_t)N * 64); // N
    int*   rowptr = cnt + N;                    // N
    int*   cursor = rowptr + N;                 // N
    int*   part   = cursor + N;                 // 256
    int*   bucket = part + 256;                 // E

    const int nPart = (N + SCAN_CHUNK - 1) / SCAN_CHUNK;   // 98 for N=100K

    hipMemsetAsync(cnt, 0, (size_t)N * sizeof(int), stream);

    transform_kernel<<<512, 256, 0, stream>>>(x, weight, bias, h, N);
    hist_kernel<<<2048, 256, 0, stream>>>(dst, cnt, E);
    scan_partial<<<nPart, 256, 0, stream>>>(cnt, rowptr, part, N);
    scan_parts<<<1, 256, 0, stream>>>(part, nPart);
    scan_add<<<256, 256, 0, stream>>>(rowptr, cursor, part, N);
    bucket_kernel<<<2048, 256, 0, stream>>>(src, dst, cursor, bucket, E, N);
    gather_reduce_kernel<<<(N + 3) / 4, 256, 0, stream>>>(rowptr, cnt, bucket, h, out, N);
}

// Round 14
// 331.835 us; speedup vs baseline: 1.3142x; 1.0239x over previous
//
#include <hip/hip_runtime.h>
#include <math.h>

#define EPS 1e-7f
#define MAX_NORM (1.0f - 1e-5f)
#define SCAN_CHUNK 1024   // elements per scan block (256 thr x 4)

__device__ __forceinline__ float waveReduceSum(float v) {
    #pragma unroll
    for (int off = 32; off > 0; off >>= 1) v += __shfl_xor(v, off, 64);
    return v;
}

// ---------------------------------------------------------------------------
// Phase 1 (fused): hyperbolic transform (r13 thread-per-row, proven) +
// degree histogram (r14: int4-vectorized, overlaps transform's VALU phase).
// ---------------------------------------------------------------------------
__global__ __launch_bounds__(256) void transform_hist_kernel(
    const float* __restrict__ x, const float* __restrict__ weight,
    const float* __restrict__ bias, const int* __restrict__ dst,
    float* __restrict__ h, int* __restrict__ cnt, int N, int E)
{
    __shared__ float wlds[64 * 64];
    __shared__ float bh[64];

    const int tid  = threadIdx.x;
    const int lane = tid & 63;
    const int wave = tid >> 6;

    for (int idx = tid; idx < 64 * 64; idx += 256) wlds[idx] = weight[idx];
    __syncthreads();

    // expmap0 on W rows + bias (block-redundant setup; wave reductions ok here)
    for (int r = wave; r < 64; r += 4) {
        float v  = wlds[r * 64 + lane];
        float ss = waveReduceSum(v * v);
        float n  = fmaxf(sqrtf(ss), EPS);
        wlds[r * 64 + lane] = v * (tanhf(n) / n);
    }
    if (wave == 0) {
        float b  = bias[lane];
        float ss = waveReduceSum(b * b);
        float n  = fmaxf(sqrtf(ss), EPS);
        bh[lane] = b * (tanhf(n) / n);
    }
    __syncthreads();

    const float4* __restrict__ w4  = reinterpret_cast<const float4*>(wlds);
    const float4* __restrict__ bh4 = reinterpret_cast<const float4*>(bh);

    const int gid    = blockIdx.x * blockDim.x + tid;
    const int stride = gridDim.x * blockDim.x;

    // ---- transform: one thread per row ----
    for (int row = gid; row < N; row += stride) {
        const float4* xr = reinterpret_cast<const float4*>(x + (size_t)row * 64);

        float4 acc[16];
        #pragma unroll
        for (int d = 0; d < 16; ++d) acc[d] = make_float4(0.f, 0.f, 0.f, 0.f);
        float ss = 0.f;

        #pragma unroll 2
        for (int k4 = 0; k4 < 16; ++k4) {
            const float4 xq = xr[k4];
            ss = fmaf(xq.x, xq.x, fmaf(xq.y, xq.y, fmaf(xq.z, xq.z, fmaf(xq.w, xq.w, ss))));
            const float xs0 = xq.x, xs1 = xq.y, xs2 = xq.z, xs3 = xq.w;
            const float4* wr0 = w4 + (k4 * 4 + 0) * 16;
            const float4* wr1 = w4 + (k4 * 4 + 1) * 16;
            const float4* wr2 = w4 + (k4 * 4 + 2) * 16;
            const float4* wr3 = w4 + (k4 * 4 + 3) * 16;
            #pragma unroll
            for (int d = 0; d < 16; ++d) {
                float4 w0 = wr0[d], w1 = wr1[d], w2 = wr2[d], w3 = wr3[d];
                float4 a = acc[d];
                a.x = fmaf(xs0, w0.x, a.x); a.y = fmaf(xs0, w0.y, a.y);
                a.z = fmaf(xs0, w0.z, a.z); a.w = fmaf(xs0, w0.w, a.w);
                a.x = fmaf(xs1, w1.x, a.x); a.y = fmaf(xs1, w1.y, a.y);
                a.z = fmaf(xs1, w1.z, a.z); a.w = fmaf(xs1, w1.w, a.w);
                a.x = fmaf(xs2, w2.x, a.x); a.y = fmaf(xs2, w2.y, a.y);
                a.z = fmaf(xs2, w2.z, a.z); a.w = fmaf(xs2, w2.w, a.w);
                a.x = fmaf(xs3, w3.x, a.x); a.y = fmaf(xs3, w3.y, a.y);
                a.z = fmaf(xs3, w3.z, a.z); a.w = fmaf(xs3, w3.w, a.w);
                acc[d] = a;
            }
        }

        float mss = 0.f;
        #pragma unroll
        for (int d = 0; d < 16; ++d) {
            float4 a = acc[d];
            mss = fmaf(a.x, a.x, fmaf(a.y, a.y, fmaf(a.z, a.z, fmaf(a.w, a.w, mss))));
        }
        const float xn  = fmaxf(sqrtf(ss), EPS);
        const float mxn = fmaxf(sqrtf(mss), EPS);
        const float xc  = fminf(xn, 1.0f - 1e-7f);
        const float at  = 0.5f * log1pf(2.0f * xc / (1.0f - xc));
        const float scale = tanhf(mxn / xn * at) / mxn;

        float dotab = 0.f, y2 = 0.f;
        #pragma unroll
        for (int d = 0; d < 16; ++d) {
            float4 b = bh4[d];
            float4 a = acc[d];
            dotab = fmaf(a.x, b.x, fmaf(a.y, b.y, fmaf(a.z, b.z, fmaf(a.w, b.w, dotab))));
            y2    = fmaf(b.x, b.x, fmaf(b.y, b.y, fmaf(b.z, b.z, fmaf(b.w, b.w, y2))));
        }
        const float xy = scale * dotab;
        const float x2 = scale * scale * mss;
        const float A  = 1.0f + 2.0f * xy + y2;
        const float B  = 1.0f - x2;
        const float rden = 1.0f / fmaxf(1.0f + 2.0f * xy + x2 * y2, EPS);

        float4* hr = reinterpret_cast<float4*>(h + (size_t)row * 64);
        #pragma unroll
        for (int d = 0; d < 16; ++d) {
            float4 b = bh4[d];
            float4 a = acc[d];
            float4 r;
            r.x = (A * (a.x * scale) + B * b.x) * rden;
            r.y = (A * (a.y * scale) + B * b.y) * rden;
            r.z = (A * (a.z * scale) + B * b.z) * rden;
            r.w = (A * (a.w * scale) + B * b.w) * rden;
            hr[d] = r;
        }
    }

    // ---- hist: int4 edge stream, 4 edges per dependent load ----
    const int4* dst4 = reinterpret_cast<const int4*>(dst);
    const int E4 = E >> 2;
    for (int i = gid; i < E4; i += stride) {
        const int4 d = dst4[i];
        atomicAdd(&cnt[d.x], 1);
        atomicAdd(&cnt[d.y], 1);
        atomicAdd(&cnt[d.z], 1);
        atomicAdd(&cnt[d.w], 1);
    }
    for (int e = (E4 << 2) + gid; e < E; e += stride)
        atomicAdd(&cnt[dst[e]], 1);
}

// ---------------------------------------------------------------------------
// Phase 2b: exclusive scan of cnt -> rowptr (+cursor copy)
// ---------------------------------------------------------------------------
__global__ __launch_bounds__(256) void scan_partial(
    const int* __restrict__ cnt, int* __restrict__ pre,
    int* __restrict__ part, int n)
{
    __shared__ int s[256];
    const int tid  = threadIdx.x;
    const int base = blockIdx.x * SCAN_CHUNK + tid * 4;
    int v0 = (base + 0 < n) ? cnt[base + 0] : 0;
    int v1 = (base + 1 < n) ? cnt[base + 1] : 0;
    int v2 = (base + 2 < n) ? cnt[base + 2] : 0;
    int v3 = (base + 3 < n) ? cnt[base + 3] : 0;
    int tsum = v0 + v1 + v2 + v3;
    s[tid] = tsum;
    __syncthreads();
    for (int off = 1; off < 256; off <<= 1) {
        int t = (tid >= off) ? s[tid - off] : 0;
        __syncthreads();
        s[tid] += t;
        __syncthreads();
    }
    int excl = s[tid] - tsum;
    if (base + 0 < n) pre[base + 0] = excl;
    if (base + 1 < n) pre[base + 1] = excl + v0;
    if (base + 2 < n) pre[base + 2] = excl + v0 + v1;
    if (base + 3 < n) pre[base + 3] = excl + v0 + v1 + v2;
    if (tid == 255) part[blockIdx.x] = s[255];
}

__global__ __launch_bounds__(256) void scan_parts(int* __restrict__ part, int nPart)
{
    __shared__ int s[256];
    const int tid = threadIdx.x;
    int v = (tid < nPart) ? part[tid] : 0;
    s[tid] = v;
    __syncthreads();
    for (int off = 1; off < 256; off <<= 1) {
        int t = (tid >= off) ? s[tid - off] : 0;
        __syncthreads();
        s[tid] += t;
        __syncthreads();
    }
    if (tid < nPart) part[tid] = s[tid] - v;  // exclusive
}

__global__ __launch_bounds__(256) void scan_add(
    int* __restrict__ pre, int* __restrict__ cursor,
    const int* __restrict__ part, int n)
{
    const int stride = gridDim.x * blockDim.x;
    for (int i = blockIdx.x * blockDim.x + threadIdx.x; i < n; i += stride) {
        int v = pre[i] + part[i / SCAN_CHUNK];
        pre[i] = v;        // rowptr
        cursor[i] = v;     // bucket cursor
    }
}

// ---------------------------------------------------------------------------
// Phase 2c: XCD-partitioned bucket scatter (r8, proven) with r14 int4
// vectorized edge stream: 4 edges per dependent load (was 6.1K cyc/iter,
// latency-bound at VALUBusy 4.7% / HBM 22.7%).
// ---------------------------------------------------------------------------
__global__ __launch_bounds__(256) void bucket_kernel(
    const int* __restrict__ src, const int* __restrict__ dst,
    int* __restrict__ cursor, int* __restrict__ bucket, int E, int N)
{
    const int group = blockIdx.x & 7;
    const int gblk  = blockIdx.x >> 3;
    const int nblk  = gridDim.x >> 3;
    const int lo = (int)(((long long)N * group) >> 3);
    const int hi = (int)(((long long)N * (group + 1)) >> 3);
    const int stride = nblk * 256;

    const int4* dst4 = reinterpret_cast<const int4*>(dst);
    const int4* src4 = reinterpret_cast<const int4*>(src);
    const int E4 = E >> 2;

    for (int i = gblk * 256 + threadIdx.x; i < E4; i += stride) {
        const int4 d = dst4[i];
        const bool a0 = (d.x >= lo) & (d.x < hi);
        const bool a1 = (d.y >= lo) & (d.y < hi);
        const bool a2 = (d.z >= lo) & (d.z < hi);
        const bool a3 = (d.w >= lo) & (d.w < hi);
        if (a0 | a1 | a2 | a3) {
            const int4 s = src4[i];
            if (a0) { int p = atomicAdd(&cursor[d.x], 1); bucket[p] = s.x; }
            if (a1) { int p = atomicAdd(&cursor[d.y], 1); bucket[p] = s.y; }
            if (a2) { int p = atomicAdd(&cursor[d.z], 1); bucket[p] = s.z; }
            if (a3) { int p = atomicAdd(&cursor[d.w], 1); bucket[p] = s.w; }
        }
    }
    for (int e = (E4 << 2) + gblk * 256 + threadIdx.x; e < E; e += stride) {
        const int d = dst[e];
        if (d >= lo && d < hi) {
            int p = atomicAdd(&cursor[d], 1);
            bucket[p] = src[e];
        }
    }
}

// ---------------------------------------------------------------------------
// Phase 3: per-node gather-reduce + mean + projection (r9 4-acc ILP, proven)
// ---------------------------------------------------------------------------
__global__ __launch_bounds__(256) void gather_reduce_kernel(
    const int* __restrict__ rowptr, const int* __restrict__ cnt,
    const int* __restrict__ bucket, const float* __restrict__ h,
    float* __restrict__ out, int N)
{
    const int lane = threadIdx.x & 63;
    const int wave = threadIdx.x >> 6;
    const int i = blockIdx.x * 4 + wave;
    if (i >= N) return;

    const int start = rowptr[i];
    const int deg   = cnt[i];
    const int end   = start + deg;

    float a0 = 0.f, a1 = 0.f, a2 = 0.f, a3 = 0.f;
    for (int c = start; c < end; c += 64) {
        const int m  = min(64, end - c);
        const int my = (lane < m) ? bucket[c + lane] : 0;
        int j = 0;
        for (; j + 4 <= m; j += 4) {
            const int s0 = __shfl(my, j + 0, 64);
            const int s1 = __shfl(my, j + 1, 64);
            const int s2 = __shfl(my, j + 2, 64);
            const int s3 = __shfl(my, j + 3, 64);
            a0 += h[(size_t)s0 * 64 + lane];
            a1 += h[(size_t)s1 * 64 + lane];
            a2 += h[(size_t)s2 * 64 + lane];
            a3 += h[(size_t)s3 * 64 + lane];
        }
        for (; j < m; ++j) {
            const int s = __shfl(my, j, 64);
            a0 += h[(size_t)s * 64 + lane];
        }
    }
    float acc = (a0 + a1) + (a2 + a3);

    float v = acc / fmaxf((float)deg, 1.0f);
    float ss = waveReduceSum(v * v);
    float n  = fmaxf(sqrtf(ss), EPS);
    if (n > MAX_NORM) v = v / n * MAX_NORM;
    out[(size_t)i * 64 + lane] = v;
}

extern "C" void kernel_launch(void* const* d_in, const int* in_sizes, int n_in,
                              void* d_out, int out_size, void* d_ws, size_t ws_size,
                              hipStream_t stream)
{
    const float* x      = (const float*)d_in[0];
    const float* weight = (const float*)d_in[1];
    const float* bias   = (const float*)d_in[2];
    const int*   ei     = (const int*)d_in[3];
    const int N = in_sizes[0] / 64;
    const int E = in_sizes[3] / 2;
    const int* src = ei;
    const int* dst = ei + E;

    float* out = (float*)d_out;

    // workspace layout (~33 MB)
    float* h      = (float*)d_ws;               // N*64 floats
    int*   cnt    = (int*)(h + (size_t)N * 64); // N
    int*   rowptr = cnt + N;                    // N
    int*   cursor = rowptr + N;                 // N
    int*   part   = cursor + N;                 // 256
    int*   bucket = part + 256;                 // E

    const int nPart = (N + SCAN_CHUNK - 1) / SCAN_CHUNK;   // 98 for N=100K

    hipMemsetAsync(cnt, 0, (size_t)N * sizeof(int), stream);

    transform_hist_kernel<<<1024, 256, 0, stream>>>(x, weight, bias, dst, h, cnt, N, E);
    scan_partial<<<nPart, 256, 0, stream>>>(cnt, rowptr, part, N);
    scan_parts<<<1, 256, 0, stream>>>(part, nPart);
    scan_add<<<256, 256, 0, stream>>>(rowptr, cursor, part, N);
    bucket_kernel<<<2048, 256, 0, stream>>>(src, dst, cursor, bucket, E, N);
    gather_reduce_kernel<<<(N + 3) / 4, 256, 0, stream>>>(rowptr, cnt, bucket, h, out, N);
}